// Round 3
// baseline (1206.739 us; speedup 1.0000x reference)
//
#include <hip/hip_runtime.h>
#include <hip/hip_bf16.h>

#define D_ 768
#define W_ 128
#define T_ 64
#define S_ 256
#define H_ 12
#define BT_ 512

// K1: q[bt][d] = mean over 16x16 patch of x[b,d,:,:]  (one block per (b,d) plane)
__global__ __launch_bounds__(256) void k_q(const float* __restrict__ x, float* __restrict__ q) {
  const int bd = blockIdx.x;
  const int tid = threadIdx.x;
  const float4* xp = (const float4*)(x + (size_t)bd * (W_*W_));
  float acc[8] = {0,0,0,0,0,0,0,0};
  #pragma unroll
  for (int k = 0; k < 16; ++k) {
    float4 v = xp[k*256 + tid];
    acc[k>>1] += (v.x + v.y) + (v.z + v.w);
  }
  __shared__ float part[256][9];
  #pragma unroll
  for (int i = 0; i < 8; ++i) part[tid][i] = acc[i];
  __syncthreads();
  if (tid < 64) {
    const int ti = tid >> 3, tj = tid & 7;
    float s = 0.f;
    #pragma unroll
    for (int m = 0; m < 8; ++m)
      #pragma unroll
      for (int n = 0; n < 4; ++n)
        s += part[m*32 + tj*4 + n][ti];
    const int b = bd / D_, d = bd - b*D_;
    q[(size_t)(b*T_ + tid)*D_ + d] = s * (1.0f/256.0f);
  }
}

// K2a: qp[bt][j] = q[bt][:] . Wq[j][:] + bq[j]   (tiled GEMM, 384 blocks)
__global__ __launch_bounds__(256) void k_qp(const float* __restrict__ q,
                                            const float* __restrict__ ipw,
                                            const float* __restrict__ ipb,
                                            float* __restrict__ qp) {
  const int jt = blockIdx.x >> 5;
  const int bt0 = (blockIdx.x & 31) * 16;
  const int tid = threadIdx.x;
  const float* Wr = ipw + (size_t)jt*64*D_;
  __shared__ float wt[64][65];
  __shared__ float at[16][65];
  const int i = tid & 63, qw = tid >> 6;
  float acc[4] = {0,0,0,0};
  for (int dc = 0; dc < D_; dc += 64) {
    #pragma unroll
    for (int k = 0; k < 4; ++k) {
      const int idx = k*256 + tid;
      const int r = idx >> 4, c4 = idx & 15;
      *(float4*)&wt[r][c4*4] = *(const float4*)(Wr + (size_t)r*D_ + dc + c4*4);
    }
    {
      const int r = tid >> 4, c4 = tid & 15;
      *(float4*)&at[r][c4*4] = *(const float4*)(q + (size_t)(bt0 + r)*D_ + dc + c4*4);
    }
    __syncthreads();
    #pragma unroll
    for (int dd = 0; dd < 64; ++dd) {
      const float wv = wt[i][dd];
      #pragma unroll
      for (int k = 0; k < 4; ++k)
        acc[k] += at[qw + k*4][dd] * wv;
    }
    __syncthreads();
  }
  const float bqv = ipb[jt*64 + i];
  #pragma unroll
  for (int k = 0; k < 4; ++k)
    qp[(size_t)(bt0 + qw + k*4)*D_ + jt*64 + i] = acc[k] + bqv;
}

// K2b: qk[bt][h][dd] = 0.125 * sum_{i<64} qp[bt][h*64+i] * Wk[h*64+i][dd]
// grid 2304 = 16 bt-chunks x (12 h x 12 dd-chunks)
__global__ __launch_bounds__(256) void k_fold(const float* __restrict__ qp,
                                              const float* __restrict__ ipw,
                                              float* __restrict__ qkout) {
  const int btc = blockIdx.x & 15;
  const int nt  = blockIdx.x >> 4;          // 0..143
  const int h   = nt / 12;
  const int ddc = (nt % 12) * 64;
  const int bt0 = btc * 32;
  const int tid = threadIdx.x;
  __shared__ float qpl[32][68];
  __shared__ float wkl[64][68];
  #pragma unroll
  for (int k = 0; k < 2; ++k) {
    const int idx = k*256 + tid;
    const int r = idx >> 4, c4 = idx & 15;
    *(float4*)&qpl[r][c4*4] = *(const float4*)(qp + (size_t)(bt0 + r)*D_ + h*64 + c4*4);
  }
  #pragma unroll
  for (int k = 0; k < 4; ++k) {
    const int idx = k*256 + tid;
    const int r = idx >> 4, c4 = idx & 15;
    *(float4*)&wkl[r][c4*4] = *(const float4*)(ipw + (size_t)(D_ + h*64 + r)*D_ + ddc + c4*4);
  }
  __syncthreads();
  const int i = tid & 63, qw = tid >> 6;
  float acc[8] = {0,0,0,0,0,0,0,0};
  #pragma unroll 8
  for (int kk = 0; kk < 64; ++kk) {
    const float w = wkl[kk][i];
    #pragma unroll
    for (int k = 0; k < 8; ++k)
      acc[k] += qpl[qw + k*4][kk] * w;
  }
  #pragma unroll
  for (int k = 0; k < 8; ++k)
    qkout[((size_t)(bt0 + qw + k*4)*H_ + h)*D_ + ddc + i] = acc[k] * 0.125f;
}

// K3: attention per (bt, head-triple): scores -> softmax -> wsum -> ctx proj
// grid 2048: bt = blockIdx>>2, hg = blockIdx&3 (4 adjacent blocks share a patch)
__global__ __launch_bounds__(256, 6) void k_attn2(const float* __restrict__ x,
                                                  const float* __restrict__ qkin,
                                                  const float* __restrict__ ipw,
                                                  const float* __restrict__ ipb,
                                                  float* __restrict__ ctx) {
  const int bt = blockIdx.x >> 2;
  const int hg = blockIdx.x & 3;
  const int b = bt >> 6, t = bt & 63;
  const int ti = t >> 3, tj = t & 7;
  const int tid = threadIdx.x;
  __shared__ float qkl[3 * D_];   // 9 KB; reused as w-stage for ctx phase
  __shared__ float sc[3][S_];     // 3 KB
  const float* xb = x + (size_t)b*D_*W_*W_ + ti*16*W_ + tj*16;

  { // load qk for 3 heads
    const float4* src = (const float4*)(qkin + ((size_t)bt*H_ + hg*3)*D_);
    float4* dst = (float4*)qkl;
    #pragma unroll
    for (int k = 0; k < 3; ++k) {
      const int idx = k*256 + tid;
      if (idx < 576) dst[idx] = src[idx];
    }
  }
  __syncthreads();

  // scores[hh][s=tid] = qk_hh . kv_s
  float acc3[3] = {0.f, 0.f, 0.f};
  #pragma unroll
  for (int c = 0; c < 3; ++c) {
    const float* chp = xb + (size_t)(3*tid + c)*(W_*W_);
    for (int blk = 0; blk < 8; ++blk) {
      float4 v[8];
      #pragma unroll
      for (int u = 0; u < 8; ++u) {
        const int pg = blk*8 + u;
        v[u] = *(const float4*)(chp + (pg>>2)*W_ + (pg&3)*4);
      }
      const int dbase = c*256 + blk*32;
      #pragma unroll
      for (int hh = 0; hh < 3; ++hh) {
        const float4* qh = (const float4*)(qkl + hh*D_ + dbase);
        float s0 = 0.f;
        #pragma unroll
        for (int u = 0; u < 8; ++u) {
          const float4 qq = qh[u];
          s0 += qq.x*v[u].x + qq.y*v[u].y + qq.z*v[u].z + qq.w*v[u].w;
        }
        acc3[hh] += s0;
      }
    }
  }
  #pragma unroll
  for (int hh = 0; hh < 3; ++hh) sc[hh][tid] = acc3[hh];
  __syncthreads();

  // softmax over s: wave w (<3) handles head w
  {
    const int wv = tid >> 6, lane = tid & 63;
    if (wv < 3) {
      float4 v = *(const float4*)(&sc[wv][lane*4]);
      float m = fmaxf(fmaxf(v.x, v.y), fmaxf(v.z, v.w));
      #pragma unroll
      for (int off = 32; off > 0; off >>= 1) m = fmaxf(m, __shfl_xor(m, off));
      const float e0 = __expf(v.x - m), e1 = __expf(v.y - m),
                  e2 = __expf(v.z - m), e3 = __expf(v.w - m);
      float ss = (e0+e1)+(e2+e3);
      #pragma unroll
      for (int off = 32; off > 0; off >>= 1) ss += __shfl_xor(ss, off);
      const float inv = 1.0f / ss;
      *(float4*)(&sc[wv][lane*4]) = make_float4(e0*inv, e1*inv, e2*inv, e3*inv);
    }
  }
  __syncthreads();

  // wsum: thread = pixel p: w[hh][c*256+p] = sum_s attn[hh][s] * x[b][3s+c][p]
  float wacc[3][3];
  #pragma unroll
  for (int hh = 0; hh < 3; ++hh) { wacc[hh][0]=0.f; wacc[hh][1]=0.f; wacc[hh][2]=0.f; }
  const float* xp0 = xb + (tid>>4)*W_ + (tid&15);
  for (int s = 0; s < S_; ++s) {
    const float p0 = xp0[(size_t)(3*s+0)*(W_*W_)];
    const float p1 = xp0[(size_t)(3*s+1)*(W_*W_)];
    const float p2 = xp0[(size_t)(3*s+2)*(W_*W_)];
    #pragma unroll
    for (int hh = 0; hh < 3; ++hh) {
      const float at = sc[hh][s];
      wacc[hh][0] += at*p0; wacc[hh][1] += at*p1; wacc[hh][2] += at*p2;
    }
  }
  __syncthreads();                 // qkl reads long done; safe to overwrite
  #pragma unroll
  for (int hh = 0; hh < 3; ++hh)
    #pragma unroll
    for (int c = 0; c < 3; ++c)
      qkl[hh*D_ + c*256 + tid] = wacc[hh][c];
  __syncthreads();

  // ctx proj: thread t<192 -> (hh = t>>6, i = t&63): ctx = w[hh] . Wv_row + bv
  if (tid < 192) {
    const int hh = tid >> 6, i = tid & 63;
    const int hglob = hg*3 + hh;
    const float* wr = ipw + (size_t)(2*D_ + hglob*64 + i)*D_;
    const float4* wl = (const float4*)(qkl + hh*D_);
    float a = 0.f;
    #pragma unroll 4
    for (int d4 = 0; d4 < 192; ++d4) {
      const float4 wv = *(const float4*)(wr + d4*4);
      const float4 ww = wl[d4];
      a += wv.x*ww.x + wv.y*ww.y + wv.z*ww.z + wv.w*ww.w;
    }
    ctx[(size_t)bt*D_ + hglob*64 + i] = a + ipb[2*D_ + hglob*64 + i];
  }
}

// K4: out[bt][j] = ctx[bt][:] . ow[j][:] + ob[j]
__global__ __launch_bounds__(256) void k_out(const float* __restrict__ ctx,
                                             const float* __restrict__ ow,
                                             const float* __restrict__ ob,
                                             float* __restrict__ out) {
  const int jt = blockIdx.x >> 5;
  const int bt0 = (blockIdx.x & 31) * 16;
  const int tid = threadIdx.x;
  const float* Wr = ow + (size_t)jt*64*D_;
  __shared__ float wt[64][65];
  __shared__ float at[16][65];
  const int i = tid & 63, qw = tid >> 6;
  float acc[4] = {0,0,0,0};
  for (int dc = 0; dc < D_; dc += 64) {
    #pragma unroll
    for (int k = 0; k < 4; ++k) {
      const int idx = k*256 + tid;
      const int r = idx >> 4, c4 = idx & 15;
      *(float4*)&wt[r][c4*4] = *(const float4*)(Wr + (size_t)r*D_ + dc + c4*4);
    }
    {
      const int r = tid >> 4, c4 = tid & 15;
      *(float4*)&at[r][c4*4] = *(const float4*)(ctx + (size_t)(bt0 + r)*D_ + dc + c4*4);
    }
    __syncthreads();
    #pragma unroll
    for (int dd = 0; dd < 64; ++dd) {
      const float wv = wt[i][dd];
      #pragma unroll
      for (int k = 0; k < 4; ++k)
        acc[k] += at[qw + k*4][dd] * wv;
    }
    __syncthreads();
  }
  const float obv = ob[jt*64 + i];
  #pragma unroll
  for (int k = 0; k < 4; ++k)
    out[(size_t)(bt0 + qw + k*4)*D_ + jt*64 + i] = acc[k] + obv;
}

extern "C" void kernel_launch(void* const* d_in, const int* in_sizes, int n_in,
                              void* d_out, int out_size, void* d_ws, size_t ws_size,
                              hipStream_t stream) {
  const float* x   = (const float*)d_in[0];
  const float* ipw = (const float*)d_in[1];
  const float* ipb = (const float*)d_in[2];
  const float* ow  = (const float*)d_in[3];
  const float* ob  = (const float*)d_in[4];
  float* out = (float*)d_out;

  float* q    = (float*)d_ws;                     // 512*768       = 1.5 MB
  float* qp   = q    + (size_t)BT_*D_;            // 512*768       = 1.5 MB
  float* qk   = qp   + (size_t)BT_*D_;            // 512*12*768    = 18.9 MB
  float* ctxb = qk   + (size_t)BT_*H_*D_;         // 512*768       = 1.5 MB

  k_q    <<<dim3(8*D_), dim3(256), 0, stream>>>(x, q);
  k_qp   <<<dim3(384),  dim3(256), 0, stream>>>(q, ipw, ipb, qp);
  k_fold <<<dim3(2304), dim3(256), 0, stream>>>(qp, ipw, qk);
  k_attn2<<<dim3(2048), dim3(256), 0, stream>>>(x, qk, ipw, ipb, ctxb);
  k_out  <<<dim3(384),  dim3(256), 0, stream>>>(ctxb, ow, ob, out);
}

// Round 5
// 534.871 us; speedup vs baseline: 2.2561x; 2.2561x over previous
//
#include <hip/hip_runtime.h>
#include <hip/hip_bf16.h>

#define D_ 768
#define W_ 128
#define T_ 64
#define S_ 256
#define H_ 12
#define BT_ 512

__device__ __forceinline__ unsigned short f2bf(float f) {
  unsigned u = __float_as_uint(f);
  u = (u + 0x7FFFu + ((u >> 16) & 1u)) >> 16;
  return (unsigned short)u;
}

// K0: pack x -> packed[bt][dd][s] (bf16) + pooled q[bt][d] (fp32).
//   dd = c*256 + p (c = ch%3, p = pixel r*16+cl), s = ch/3.
// Block: one (b, ti, tj-pair) x one channel-half (384 ch). 512 threads.
// Reads full 128B lines (2 patches = 32 cols); LDS transpose; coalesced stores.
__global__ __launch_bounds__(512) void k_pack(const float* __restrict__ x,
                                              unsigned short* __restrict__ packed,
                                              float* __restrict__ q) {
  const int blk  = blockIdx.x;
  const int half = blk & 1;
  const int tjp  = (blk >> 1) & 3;
  const int ti   = (blk >> 3) & 7;
  const int b    = blk >> 6;
  const int tid  = threadIdx.x;
  const int w    = tid >> 6, lane = tid & 63;
  const int btg0 = b*64 + ti*8 + tjp*2;

  __shared__ unsigned short tile[48][2][260];   // 49.9 KB
  __shared__ float poolacc[48][2][2];

  const float* xrow = x + (size_t)b*D_*16384 + (16*ti)*128 + 32*tjp;

  const int ccS = half*8, ccE = ccS + 8;
  for (int cc = ccS; cc < ccE; ++cc) {
    const int ch0 = cc * 48;
    __syncthreads();   // protect tile/poolacc from previous readout

    // ---- read phase: 48 ch x 16 r x 32 cols fp32, full-line coalesced ----
    #pragma unroll
    for (int it = 0; it < 12; ++it) {
      const int idx = it*512 + tid;
      const int c8 = idx & 7;            // col-quad in 32 cols
      const int r  = (idx >> 3) & 15;
      const int ch = idx >> 7;           // 0..47
      const float4 v = *(const float4*)(xrow + (size_t)(ch0 + ch)*16384 + r*128 + c8*4);
      const int btl = c8 >> 2;
      const int px  = r*16 + (c8 & 3)*4;
      unsigned lo = (unsigned)f2bf(v.x) | ((unsigned)f2bf(v.y) << 16);
      unsigned hi = (unsigned)f2bf(v.z) | ((unsigned)f2bf(v.w) << 16);
      *(uint2*)&tile[ch][btl][px] = make_uint2(lo, hi);
      // pooled sum: reduce 16 cols (xor 1,2) then 8 rows (xor 8,16,32)
      float ps = (v.x + v.y) + (v.z + v.w);
      ps += __shfl_xor(ps, 1);
      ps += __shfl_xor(ps, 2);
      ps += __shfl_xor(ps, 8);
      ps += __shfl_xor(ps, 16);
      ps += __shfl_xor(ps, 32);
      if (lane == 0 || lane == 4) {
        const int chw  = it*4 + (w >> 1);   // wave-uniform ch
        const int hwv  = w & 1;             // which 8-row half
        poolacc[chw][lane >> 2][hwv] = ps;
      }
    }
    __syncthreads();

    // ---- readout: thread = (patch btl, pixel p); 16 s per chunk ----
    {
      const int btl = tid >> 8, p = tid & 255;
      const int s0 = cc * 16;
      unsigned short* pb = packed + (size_t)(btg0 + btl)*D_*S_ + s0;
      #pragma unroll
      for (int c = 0; c < 3; ++c) {
        unsigned u[8];
        #pragma unroll
        for (int k2 = 0; k2 < 8; ++k2) {
          const unsigned a  = tile[3*(2*k2)     + c][btl][p];
          const unsigned b2 = tile[3*(2*k2 + 1) + c][btl][p];
          u[k2] = a | (b2 << 16);
        }
        unsigned short* dst = pb + (size_t)(c*256 + p)*S_;
        *(uint4*)(dst)     = make_uint4(u[0], u[1], u[2], u[3]);
        *(uint4*)(dst + 8) = make_uint4(u[4], u[5], u[6], u[7]);
      }
      // pool finalize for this chunk's 48 channels
      if (tid < 96) {
        const int ch = tid >> 1, bl = tid & 1;
        q[(size_t)(btg0 + bl)*D_ + ch0 + ch] =
            (poolacc[ch][bl][0] + poolacc[ch][bl][1]) * (1.0f/256.0f);
      }
    }
  }
}

// K2a: qp[bt][j] = q[bt][:] . Wq[j][:] + bq[j]   (tiled GEMM, 384 blocks)
__global__ __launch_bounds__(256) void k_qp(const float* __restrict__ q,
                                            const float* __restrict__ ipw,
                                            const float* __restrict__ ipb,
                                            float* __restrict__ qp) {
  const int jt = blockIdx.x >> 5;
  const int bt0 = (blockIdx.x & 31) * 16;
  const int tid = threadIdx.x;
  const float* Wr = ipw + (size_t)jt*64*D_;
  __shared__ float wt[64][65];
  __shared__ float at[16][65];
  const int i = tid & 63, qw = tid >> 6;
  float acc[4] = {0,0,0,0};
  for (int dc = 0; dc < D_; dc += 64) {
    #pragma unroll
    for (int k = 0; k < 4; ++k) {
      const int idx = k*256 + tid;
      const int r = idx >> 4, c4 = idx & 15;
      *(float4*)&wt[r][c4*4] = *(const float4*)(Wr + (size_t)r*D_ + dc + c4*4);
    }
    {
      const int r = tid >> 4, c4 = tid & 15;
      *(float4*)&at[r][c4*4] = *(const float4*)(q + (size_t)(bt0 + r)*D_ + dc + c4*4);
    }
    __syncthreads();
    #pragma unroll
    for (int dd = 0; dd < 64; ++dd) {
      const float wv = wt[i][dd];
      #pragma unroll
      for (int k = 0; k < 4; ++k)
        acc[k] += at[qw + k*4][dd] * wv;
    }
    __syncthreads();
  }
  const float bqv = ipb[jt*64 + i];
  #pragma unroll
  for (int k = 0; k < 4; ++k)
    qp[(size_t)(bt0 + qw + k*4)*D_ + jt*64 + i] = acc[k] + bqv;
}

// K2b: qk[bt][h][dd] = 0.125 * sum_{i<64} qp[bt][h*64+i] * Wk[h*64+i][dd]
__global__ __launch_bounds__(256) void k_fold(const float* __restrict__ qp,
                                              const float* __restrict__ ipw,
                                              float* __restrict__ qkout) {
  const int btc = blockIdx.x & 15;
  const int nt  = blockIdx.x >> 4;
  const int h   = nt / 12;
  const int ddc = (nt % 12) * 64;
  const int bt0 = btc * 32;
  const int tid = threadIdx.x;
  __shared__ float qpl[32][68];
  __shared__ float wkl[64][68];
  #pragma unroll
  for (int k = 0; k < 2; ++k) {
    const int idx = k*256 + tid;
    const int r = idx >> 4, c4 = idx & 15;
    *(float4*)&qpl[r][c4*4] = *(const float4*)(qp + (size_t)(bt0 + r)*D_ + h*64 + c4*4);
  }
  #pragma unroll
  for (int k = 0; k < 4; ++k) {
    const int idx = k*256 + tid;
    const int r = idx >> 4, c4 = idx & 15;
    *(float4*)&wkl[r][c4*4] = *(const float4*)(ipw + (size_t)(D_ + h*64 + r)*D_ + ddc + c4*4);
  }
  __syncthreads();
  const int i = tid & 63, qw = tid >> 6;
  float acc[8] = {0,0,0,0,0,0,0,0};
  #pragma unroll 8
  for (int kk = 0; kk < 64; ++kk) {
    const float w = wkl[kk][i];
    #pragma unroll
    for (int k = 0; k < 8; ++k)
      acc[k] += qpl[qw + k*4][kk] * w;
  }
  #pragma unroll
  for (int k = 0; k < 8; ++k)
    qkout[((size_t)(bt0 + qw + k*4)*H_ + h)*D_ + ddc + i] = acc[k] * 0.125f;
}

// K3: per-bt scores -> softmax -> wsum, all from packed[bt][dd][s] bf16.
__global__ __launch_bounds__(256) void k_attn3(const unsigned short* __restrict__ packed,
                                               const float* __restrict__ qkin,
                                               float* __restrict__ wout) {
  const int bt = blockIdx.x;
  const int tid = threadIdx.x;
  const int wv = tid >> 6, lane = tid & 63;
  __shared__ float qk_lds[H_*D_];   // 36 KB; reused as partial-score scratch
  __shared__ float sc[H_][S_];      // 12 KB

  {
    const float4* src = (const float4*)(qkin + (size_t)bt*H_*D_);
    float4* dst = (float4*)qk_lds;
    #pragma unroll
    for (int k = 0; k < 9; ++k) dst[k*256 + tid] = src[k*256 + tid];
  }
  __syncthreads();

  // ---- scores partials: wave owns d-range, lane owns s = lane*4..+3 ----
  float acc[H_][4];
  #pragma unroll
  for (int h = 0; h < H_; ++h)
    #pragma unroll
    for (int j = 0; j < 4; ++j) acc[h][j] = 0.f;

  {
    const unsigned short* pbase = packed + (size_t)bt*D_*S_ + lane*4;
    const int d0 = wv * 192;
    #pragma unroll 4
    for (int d4 = 0; d4 < 48; ++d4) {
      const int d = d0 + d4*4;
      float f[4][4];
      #pragma unroll
      for (int dd = 0; dd < 4; ++dd) {
        const short4 pv = *(const short4*)(pbase + (size_t)(d + dd)*S_);
        f[dd][0] = __uint_as_float(((unsigned)(unsigned short)pv.x) << 16);
        f[dd][1] = __uint_as_float(((unsigned)(unsigned short)pv.y) << 16);
        f[dd][2] = __uint_as_float(((unsigned)(unsigned short)pv.z) << 16);
        f[dd][3] = __uint_as_float(((unsigned)(unsigned short)pv.w) << 16);
      }
      #pragma unroll
      for (int h = 0; h < H_; ++h) {
        const float4 qv = *(const float4*)&qk_lds[h*D_ + d];
        #pragma unroll
        for (int j = 0; j < 4; ++j)
          acc[h][j] += qv.x*f[0][j] + qv.y*f[1][j] + qv.z*f[2][j] + qv.w*f[3][j];
      }
    }
  }
  __syncthreads();   // everyone done reading qk_lds

  if (wv == 0) {
    #pragma unroll
    for (int h = 0; h < H_; ++h)
      *(float4*)&sc[h][lane*4] = make_float4(acc[h][0], acc[h][1], acc[h][2], acc[h][3]);
  } else {
    float* dstp = qk_lds + (size_t)(wv - 1)*(H_*S_);
    #pragma unroll
    for (int h = 0; h < H_; ++h)
      *(float4*)&dstp[h*S_ + lane*4] = make_float4(acc[h][0], acc[h][1], acc[h][2], acc[h][3]);
  }
  __syncthreads();
  #pragma unroll
  for (int h = 0; h < H_; ++h)
    sc[h][tid] += qk_lds[0*(H_*S_) + h*S_ + tid]
                + qk_lds[1*(H_*S_) + h*S_ + tid]
                + qk_lds[2*(H_*S_) + h*S_ + tid];
  __syncthreads();

  // ---- softmax over s (3 heads per wave) ----
  {
    #pragma unroll
    for (int hh = 0; hh < 3; ++hh) {
      const int h = wv*3 + hh;
      float4 v = *(const float4*)(&sc[h][lane*4]);
      float m = fmaxf(fmaxf(v.x, v.y), fmaxf(v.z, v.w));
      #pragma unroll
      for (int off = 32; off > 0; off >>= 1) m = fmaxf(m, __shfl_xor(m, off));
      const float e0 = __expf(v.x - m), e1 = __expf(v.y - m),
                  e2 = __expf(v.z - m), e3 = __expf(v.w - m);
      float ss = (e0+e1)+(e2+e3);
      #pragma unroll
      for (int off = 32; off > 0; off >>= 1) ss += __shfl_xor(ss, off);
      const float inv = 1.0f / ss;
      *(float4*)(&sc[h][lane*4]) = make_float4(e0*inv, e1*inv, e2*inv, e3*inv);
    }
  }
  __syncthreads();

  // ---- wsum: thread owns dd = c*256+tid; stream s via uint4 ----
  float wacc[H_][3];
  #pragma unroll
  for (int h = 0; h < H_; ++h) { wacc[h][0]=0.f; wacc[h][1]=0.f; wacc[h][2]=0.f; }
  const unsigned short* prow = packed + (size_t)bt*D_*S_;
  #pragma unroll 2
  for (int s8 = 0; s8 < 32; ++s8) {
    float f[3][8];
    #pragma unroll
    for (int c = 0; c < 3; ++c) {
      const uint4 pv = *(const uint4*)(prow + (size_t)(c*256 + tid)*S_ + s8*8);
      f[c][0] = __uint_as_float(pv.x << 16);
      f[c][1] = __uint_as_float(pv.x & 0xFFFF0000u);
      f[c][2] = __uint_as_float(pv.y << 16);
      f[c][3] = __uint_as_float(pv.y & 0xFFFF0000u);
      f[c][4] = __uint_as_float(pv.z << 16);
      f[c][5] = __uint_as_float(pv.z & 0xFFFF0000u);
      f[c][6] = __uint_as_float(pv.w << 16);
      f[c][7] = __uint_as_float(pv.w & 0xFFFF0000u);
    }
    #pragma unroll
    for (int h = 0; h < H_; ++h) {
      const float4 a0 = *(const float4*)&sc[h][s8*8];
      const float4 a1 = *(const float4*)&sc[h][s8*8 + 4];
      #pragma unroll
      for (int c = 0; c < 3; ++c)
        wacc[h][c] += a0.x*f[c][0] + a0.y*f[c][1] + a0.z*f[c][2] + a0.w*f[c][3]
                    + a1.x*f[c][4] + a1.y*f[c][5] + a1.z*f[c][6] + a1.w*f[c][7];
    }
  }
  float* wp = wout + (size_t)bt*H_*D_;
  #pragma unroll
  for (int h = 0; h < H_; ++h)
    #pragma unroll
    for (int c = 0; c < 3; ++c)
      wp[h*D_ + c*256 + tid] = wacc[h][c];
}

// ---------------- fallback path (small workspace) ----------------
__global__ __launch_bounds__(256) void k_q(const float* __restrict__ x, float* __restrict__ q) {
  const int bd = blockIdx.x;
  const int tid = threadIdx.x;
  const float4* xp = (const float4*)(x + (size_t)bd * (W_*W_));
  float acc[8] = {0,0,0,0,0,0,0,0};
  #pragma unroll
  for (int k = 0; k < 16; ++k) {
    float4 v = xp[k*256 + tid];
    acc[k>>1] += (v.x + v.y) + (v.z + v.w);
  }
  __shared__ float part[256][9];
  #pragma unroll
  for (int i = 0; i < 8; ++i) part[tid][i] = acc[i];
  __syncthreads();
  if (tid < 64) {
    const int ti = tid >> 3, tj = tid & 7;
    float s = 0.f;
    #pragma unroll
    for (int m = 0; m < 8; ++m)
      #pragma unroll
      for (int n = 0; n < 4; ++n)
        s += part[m*32 + tj*4 + n][ti];
    const int b = bd / D_, d = bd - b*D_;
    q[(size_t)(b*T_ + tid)*D_ + d] = s * (1.0f/256.0f);
  }
}

__global__ __launch_bounds__(256) void k_attn(const float* __restrict__ x,
                                              const float* __restrict__ qkin,
                                              float* __restrict__ wout) {
  const int bt = blockIdx.x;
  const int b = bt >> 6, t = bt & 63;
  const int ti = t >> 3, tj = t & 7;
  const int tid = threadIdx.x;
  __shared__ float qkl[H_*D_];
  __shared__ float sc[H_][S_];
  const float* xb = x + (size_t)b*D_*W_*W_ + ti*16*W_ + tj*16;
  {
    const float4* src = (const float4*)(qkin + (size_t)bt*H_*D_);
    float4* dst = (float4*)qkl;
    #pragma unroll
    for (int k = 0; k < 9; ++k) dst[k*256 + tid] = src[k*256 + tid];
  }
  __syncthreads();
  float acc[H_];
  #pragma unroll
  for (int h = 0; h < H_; ++h) acc[h] = 0.f;
  #pragma unroll
  for (int c = 0; c < 3; ++c) {
    const float* chp = xb + (size_t)(3*tid + c)*(W_*W_);
    for (int blk = 0; blk < 8; ++blk) {
      float4 v[8];
      #pragma unroll
      for (int u = 0; u < 8; ++u) {
        const int pg = blk*8 + u;
        v[u] = *(const float4*)(chp + (pg>>2)*W_ + (pg&3)*4);
      }
      const int dbase = c*256 + blk*32;
      #pragma unroll
      for (int h = 0; h < H_; ++h) {
        const float4* qh = (const float4*)(qkl + h*D_ + dbase);
        float s0 = 0.f;
        #pragma unroll
        for (int u = 0; u < 8; ++u) {
          const float4 qq = qh[u];
          s0 += qq.x*v[u].x + qq.y*v[u].y + qq.z*v[u].z + qq.w*v[u].w;
        }
        acc[h] += s0;
      }
    }
  }
  #pragma unroll
  for (int h = 0; h < H_; ++h) sc[h][tid] = acc[h];
  __syncthreads();
  {
    const int wv = tid >> 6, lane = tid & 63;
    #pragma unroll
    for (int hh = 0; hh < 3; ++hh) {
      const int h = wv*3 + hh;
      float4 v = *(const float4*)(&sc[h][lane*4]);
      float m = fmaxf(fmaxf(v.x, v.y), fmaxf(v.z, v.w));
      #pragma unroll
      for (int off = 32; off > 0; off >>= 1) m = fmaxf(m, __shfl_xor(m, off));
      const float e0 = __expf(v.x - m), e1 = __expf(v.y - m),
                  e2 = __expf(v.z - m), e3 = __expf(v.w - m);
      float ss = (e0+e1)+(e2+e3);
      #pragma unroll
      for (int off = 32; off > 0; off >>= 1) ss += __shfl_xor(ss, off);
      const float inv = 1.0f / ss;
      *(float4*)(&sc[h][lane*4]) = make_float4(e0*inv, e1*inv, e2*inv, e3*inv);
    }
  }
  __syncthreads();
  float wacc[H_][3];
  #pragma unroll
  for (int h = 0; h < H_; ++h) { wacc[h][0]=0.f; wacc[h][1]=0.f; wacc[h][2]=0.f; }
  const float* xp0 = xb + (tid>>4)*W_ + (tid&15);
  for (int s = 0; s < S_; ++s) {
    const float p0 = xp0[(size_t)(3*s+0)*(W_*W_)];
    const float p1 = xp0[(size_t)(3*s+1)*(W_*W_)];
    const float p2 = xp0[(size_t)(3*s+2)*(W_*W_)];
    #pragma unroll
    for (int h = 0; h < H_; ++h) {
      const float at = sc[h][s];
      wacc[h][0] += at*p0; wacc[h][1] += at*p1; wacc[h][2] += at*p2;
    }
  }
  float* wp = wout + (size_t)bt*H_*D_;
  #pragma unroll
  for (int h = 0; h < H_; ++h)
    #pragma unroll
    for (int c = 0; c < 3; ++c)
      wp[h*D_ + c*256 + tid] = wacc[h][c];
}
// ------------------------------------------------------------------

// K4a: ctx[bt][h*64+i] = sum_d w[bt][h][d] * Wv[h*64+i][d] + bv
__global__ __launch_bounds__(256) void k_ctx(const float* __restrict__ wbuf,
                                             const float* __restrict__ ipw,
                                             const float* __restrict__ ipb,
                                             float* __restrict__ ctx) {
  const int h = blockIdx.x >> 5;
  const int bt0 = (blockIdx.x & 31) * 16;
  const int tid = threadIdx.x;
  const float* Wv = ipw + (size_t)2*D_*D_ + (size_t)h*64*D_;
  __shared__ float wt[64][65];
  __shared__ float at[16][65];
  const int i = tid & 63, qw = tid >> 6;
  float acc[4] = {0,0,0,0};
  for (int dc = 0; dc < D_; dc += 64) {
    #pragma unroll
    for (int k = 0; k < 4; ++k) {
      const int idx = k*256 + tid;
      const int r = idx >> 4, c4 = idx & 15;
      *(float4*)&wt[r][c4*4] = *(const float4*)(Wv + (size_t)r*D_ + dc + c4*4);
    }
    {
      const int r = tid >> 4, c4 = tid & 15;
      *(float4*)&at[r][c4*4] = *(const float4*)(wbuf + ((size_t)(bt0 + r)*H_ + h)*D_ + dc + c4*4);
    }
    __syncthreads();
    #pragma unroll
    for (int dd = 0; dd < 64; ++dd) {
      const float wv = wt[i][dd];
      #pragma unroll
      for (int k = 0; k < 4; ++k)
        acc[k] += at[qw + k*4][dd] * wv;
    }
    __syncthreads();
  }
  const float bvv = ipb[2*D_ + h*64 + i];
  #pragma unroll
  for (int k = 0; k < 4; ++k)
    ctx[(size_t)(bt0 + qw + k*4)*D_ + h*64 + i] = acc[k] + bvv;
}

// K4b: out[bt][j] = ctx[bt][:] . ow[j][:] + ob[j]
__global__ __launch_bounds__(256) void k_out(const float* __restrict__ ctx,
                                             const float* __restrict__ ow,
                                             const float* __restrict__ ob,
                                             float* __restrict__ out) {
  const int jt = blockIdx.x >> 5;
  const int bt0 = (blockIdx.x & 31) * 16;
  const int tid = threadIdx.x;
  const float* Wr = ow + (size_t)jt*64*D_;
  __shared__ float wt[64][65];
  __shared__ float at[16][65];
  const int i = tid & 63, qw = tid >> 6;
  float acc[4] = {0,0,0,0};
  for (int dc = 0; dc < D_; dc += 64) {
    #pragma unroll
    for (int k = 0; k < 4; ++k) {
      const int idx = k*256 + tid;
      const int r = idx >> 4, c4 = idx & 15;
      *(float4*)&wt[r][c4*4] = *(const float4*)(Wr + (size_t)r*D_ + dc + c4*4);
    }
    {
      const int r = tid >> 4, c4 = tid & 15;
      *(float4*)&at[r][c4*4] = *(const float4*)(ctx + (size_t)(bt0 + r)*D_ + dc + c4*4);
    }
    __syncthreads();
    #pragma unroll
    for (int dd = 0; dd < 64; ++dd) {
      const float wv = wt[i][dd];
      #pragma unroll
      for (int k = 0; k < 4; ++k)
        acc[k] += at[qw + k*4][dd] * wv;
    }
    __syncthreads();
  }
  const float obv = ob[jt*64 + i];
  #pragma unroll
  for (int k = 0; k < 4; ++k)
    out[(size_t)(bt0 + qw + k*4)*D_ + jt*64 + i] = acc[k] + obv;
}

extern "C" void kernel_launch(void* const* d_in, const int* in_sizes, int n_in,
                              void* d_out, int out_size, void* d_ws, size_t ws_size,
                              hipStream_t stream) {
  const float* x   = (const float*)d_in[0];
  const float* ipw = (const float*)d_in[1];
  const float* ipb = (const float*)d_in[2];
  const float* ow  = (const float*)d_in[3];
  const float* ob  = (const float*)d_in[4];
  float* out = (float*)d_out;

  float* q    = (float*)d_ws;                       // 1.5 MB
  float* qp   = q    + (size_t)BT_*D_;              // 1.5 MB
  float* qk   = qp   + (size_t)BT_*D_;              // 18.9 MB
  float* wb   = qk   + (size_t)BT_*H_*D_;           // 18.9 MB
  float* ctxb = wb   + (size_t)BT_*H_*D_;           // 1.5 MB
  unsigned short* packed = (unsigned short*)(ctxb + (size_t)BT_*D_);  // 201.3 MB

  const size_t need_main = ((size_t)BT_*D_*3 + (size_t)BT_*H_*D_*2) * 4
                         + (size_t)BT_*D_*S_*2;

  if (ws_size >= need_main) {
    k_pack <<<dim3(512),  dim3(512), 0, stream>>>(x, packed, q);
    k_qp   <<<dim3(384),  dim3(256), 0, stream>>>(q, ipw, ipb, qp);
    k_fold <<<dim3(2304), dim3(256), 0, stream>>>(qp, ipw, qk);
    k_attn3<<<dim3(BT_),  dim3(256), 0, stream>>>(packed, qk, wb);
    k_ctx  <<<dim3(384),  dim3(256), 0, stream>>>(wb, ipw, ipb, ctxb);
    k_out  <<<dim3(384),  dim3(256), 0, stream>>>(ctxb, ow, ob, out);
  } else {
    k_q    <<<dim3(8*D_), dim3(256), 0, stream>>>(x, q);
    k_qp   <<<dim3(384),  dim3(256), 0, stream>>>(q, ipw, ipb, qp);
    k_fold <<<dim3(2304), dim3(256), 0, stream>>>(qp, ipw, qk);
    k_attn <<<dim3(BT_),  dim3(256), 0, stream>>>(x, qk, wb);
    k_ctx  <<<dim3(384),  dim3(256), 0, stream>>>(wb, ipw, ipb, ctxb);
    k_out  <<<dim3(384),  dim3(256), 0, stream>>>(ctxb, ow, ob, out);
  }
}

// Round 6
// 413.035 us; speedup vs baseline: 2.9216x; 1.2950x over previous
//
#include <hip/hip_runtime.h>
#include <hip/hip_bf16.h>

#define D_ 768
#define W_ 128
#define T_ 64
#define S_ 256
#define H_ 12
#define BT_ 512

__device__ __forceinline__ unsigned short f2bf(float f) {
  unsigned u = __float_as_uint(f);
  u = (u + 0x7FFFu + ((u >> 16) & 1u)) >> 16;
  return (unsigned short)u;
}

// K0: pack x -> packed[bt][sc][dd][s&15] (bf16) + pooled q[bt][d] (fp32).
//   dd = c*256 + p (c = ch%3, p = pixel r*16+cl), s = ch/3, sc = s>>4.
// Grid 4096 = (b, ti, tjp, cc); block = one 48-channel chunk (cc = sc) of a
// patch pair. Full-line reads, LDS transpose, fully-coalesced 32B/lane writes.
__global__ __launch_bounds__(512) void k_pack(const float* __restrict__ x,
                                              unsigned short* __restrict__ packed,
                                              float* __restrict__ q) {
  const int blk  = blockIdx.x;
  const int cc   = blk & 15;
  const int tjp  = (blk >> 4) & 3;
  const int ti   = (blk >> 6) & 7;
  const int b    = blk >> 9;
  const int tid  = threadIdx.x;
  const int w    = tid >> 6, lane = tid & 63;
  const int btg0 = b*64 + ti*8 + tjp*2;
  const int ch0  = cc * 48;

  __shared__ unsigned short tile[48][2][260];   // 49.9 KB
  __shared__ float poolacc[48][2][2];

  const float* xrow = x + (size_t)b*D_*16384 + (16*ti)*128 + 32*tjp;

  // ---- read phase: 48 ch x 16 r x 32 cols fp32, full-line coalesced ----
  #pragma unroll
  for (int it = 0; it < 12; ++it) {
    const int idx = it*512 + tid;
    const int c8 = idx & 7;            // col-quad in 32 cols
    const int r  = (idx >> 3) & 15;
    const int ch = idx >> 7;           // 0..47
    const float4 v = *(const float4*)(xrow + (size_t)(ch0 + ch)*16384 + r*128 + c8*4);
    const int btl = c8 >> 2;
    const int px  = r*16 + (c8 & 3)*4;
    unsigned lo = (unsigned)f2bf(v.x) | ((unsigned)f2bf(v.y) << 16);
    unsigned hi = (unsigned)f2bf(v.z) | ((unsigned)f2bf(v.w) << 16);
    *(uint2*)&tile[ch][btl][px] = make_uint2(lo, hi);
    // pooled sum: xor1,2 reduce 16 cols of one patch; xor8,16,32 reduce 8 rows
    float ps = (v.x + v.y) + (v.z + v.w);
    ps += __shfl_xor(ps, 1);
    ps += __shfl_xor(ps, 2);
    ps += __shfl_xor(ps, 8);
    ps += __shfl_xor(ps, 16);
    ps += __shfl_xor(ps, 32);
    if (lane == 0 || lane == 4) {
      const int chw = it*4 + (w >> 1);   // wave-uniform channel
      const int hwv = w & 1;             // which 8-row half
      poolacc[chw][lane >> 2][hwv] = ps;
    }
  }
  __syncthreads();

  // ---- readout: thread = (patch btl, pixel p); 16 s, 3 c-rows, 32B runs ----
  {
    const int btl = tid >> 8, p = tid & 255;
    unsigned short* pbt = packed + ((size_t)(btg0 + btl)*16 + cc)*D_*16;
    #pragma unroll
    for (int c = 0; c < 3; ++c) {
      unsigned u[8];
      #pragma unroll
      for (int k2 = 0; k2 < 8; ++k2) {
        const unsigned a  = tile[3*(2*k2)     + c][btl][p];
        const unsigned b2 = tile[3*(2*k2 + 1) + c][btl][p];
        u[k2] = a | (b2 << 16);
      }
      unsigned short* dst = pbt + (size_t)(c*256 + p)*16;
      *(uint4*)(dst)     = make_uint4(u[0], u[1], u[2], u[3]);
      *(uint4*)(dst + 8) = make_uint4(u[4], u[5], u[6], u[7]);
    }
    if (tid < 96) {
      const int ch = tid >> 1, bl = tid & 1;
      q[(size_t)(btg0 + bl)*D_ + ch0 + ch] =
          (poolacc[ch][bl][0] + poolacc[ch][bl][1]) * (1.0f/256.0f);
    }
  }
}

// K2a: qp[bt][j] = q[bt][:] . Wq[j][:] + bq[j]   (tiled GEMM, 384 blocks)
__global__ __launch_bounds__(256) void k_qp(const float* __restrict__ q,
                                            const float* __restrict__ ipw,
                                            const float* __restrict__ ipb,
                                            float* __restrict__ qp) {
  const int jt = blockIdx.x >> 5;
  const int bt0 = (blockIdx.x & 31) * 16;
  const int tid = threadIdx.x;
  const float* Wr = ipw + (size_t)jt*64*D_;
  __shared__ float wt[64][65];
  __shared__ float at[16][65];
  const int i = tid & 63, qw = tid >> 6;
  float acc[4] = {0,0,0,0};
  for (int dc = 0; dc < D_; dc += 64) {
    #pragma unroll
    for (int k = 0; k < 4; ++k) {
      const int idx = k*256 + tid;
      const int r = idx >> 4, c4 = idx & 15;
      *(float4*)&wt[r][c4*4] = *(const float4*)(Wr + (size_t)r*D_ + dc + c4*4);
    }
    {
      const int r = tid >> 4, c4 = tid & 15;
      *(float4*)&at[r][c4*4] = *(const float4*)(q + (size_t)(bt0 + r)*D_ + dc + c4*4);
    }
    __syncthreads();
    #pragma unroll
    for (int dd = 0; dd < 64; ++dd) {
      const float wv = wt[i][dd];
      #pragma unroll
      for (int k = 0; k < 4; ++k)
        acc[k] += at[qw + k*4][dd] * wv;
    }
    __syncthreads();
  }
  const float bqv = ipb[jt*64 + i];
  #pragma unroll
  for (int k = 0; k < 4; ++k)
    qp[(size_t)(bt0 + qw + k*4)*D_ + jt*64 + i] = acc[k] + bqv;
}

// K2b: qk[bt][h][dd] = 0.125 * sum_{i<64} qp[bt][h*64+i] * Wk[h*64+i][dd]
__global__ __launch_bounds__(256) void k_fold(const float* __restrict__ qp,
                                              const float* __restrict__ ipw,
                                              float* __restrict__ qkout) {
  const int btc = blockIdx.x & 15;
  const int nt  = blockIdx.x >> 4;
  const int h   = nt / 12;
  const int ddc = (nt % 12) * 64;
  const int bt0 = btc * 32;
  const int tid = threadIdx.x;
  __shared__ float qpl[32][68];
  __shared__ float wkl[64][68];
  #pragma unroll
  for (int k = 0; k < 2; ++k) {
    const int idx = k*256 + tid;
    const int r = idx >> 4, c4 = idx & 15;
    *(float4*)&qpl[r][c4*4] = *(const float4*)(qp + (size_t)(bt0 + r)*D_ + h*64 + c4*4);
  }
  #pragma unroll
  for (int k = 0; k < 4; ++k) {
    const int idx = k*256 + tid;
    const int r = idx >> 4, c4 = idx & 15;
    *(float4*)&wkl[r][c4*4] = *(const float4*)(ipw + (size_t)(D_ + h*64 + r)*D_ + ddc + c4*4);
  }
  __syncthreads();
  const int i = tid & 63, qw = tid >> 6;
  float acc[8] = {0,0,0,0,0,0,0,0};
  #pragma unroll 8
  for (int kk = 0; kk < 64; ++kk) {
    const float w = wkl[kk][i];
    #pragma unroll
    for (int k = 0; k < 8; ++k)
      acc[k] += qpl[qw + k*4][kk] * w;
  }
  #pragma unroll
  for (int k = 0; k < 8; ++k)
    qkout[((size_t)(bt0 + qw + k*4)*H_ + h)*D_ + ddc + i] = acc[k] * 0.125f;
}

// K3: per-bt scores -> softmax -> wsum from packed[bt][sc][dd][s&15] bf16.
__global__ __launch_bounds__(256) void k_attn3(const unsigned short* __restrict__ packed,
                                               const float* __restrict__ qkin,
                                               float* __restrict__ wout) {
  const int bt = blockIdx.x;
  const int tid = threadIdx.x;
  const int wv = tid >> 6, lane = tid & 63;
  __shared__ float qk_lds[H_*D_];   // 36 KB; reused as partial-score scratch
  __shared__ float sc[H_][S_];      // 12 KB

  {
    const float4* src = (const float4*)(qkin + (size_t)bt*H_*D_);
    float4* dst = (float4*)qk_lds;
    #pragma unroll
    for (int k = 0; k < 9; ++k) dst[k*256 + tid] = src[k*256 + tid];
  }
  __syncthreads();

  // ---- scores partials: wave owns d-range, lane owns s = lane*4..+3 ----
  float acc[H_][4];
  #pragma unroll
  for (int h = 0; h < H_; ++h)
    #pragma unroll
    for (int j = 0; j < 4; ++j) acc[h][j] = 0.f;

  {
    // lane's s-chunk: sc_idx = lane>>2, within-chunk offset (lane&3)*4
    const unsigned short* pb = packed + ((size_t)bt*16 + (lane >> 2))*D_*16 + (lane & 3)*4;
    const int d0 = wv * 192;
    #pragma unroll 4
    for (int d4 = 0; d4 < 48; ++d4) {
      const int d = d0 + d4*4;
      float f[4][4];
      #pragma unroll
      for (int dd = 0; dd < 4; ++dd) {
        const short4 pv = *(const short4*)(pb + (size_t)(d + dd)*16);
        f[dd][0] = __uint_as_float(((unsigned)(unsigned short)pv.x) << 16);
        f[dd][1] = __uint_as_float(((unsigned)(unsigned short)pv.y) << 16);
        f[dd][2] = __uint_as_float(((unsigned)(unsigned short)pv.z) << 16);
        f[dd][3] = __uint_as_float(((unsigned)(unsigned short)pv.w) << 16);
      }
      #pragma unroll
      for (int h = 0; h < H_; ++h) {
        const float4 qv = *(const float4*)&qk_lds[h*D_ + d];
        #pragma unroll
        for (int j = 0; j < 4; ++j)
          acc[h][j] += qv.x*f[0][j] + qv.y*f[1][j] + qv.z*f[2][j] + qv.w*f[3][j];
      }
    }
  }
  __syncthreads();   // everyone done reading qk_lds

  if (wv == 0) {
    #pragma unroll
    for (int h = 0; h < H_; ++h)
      *(float4*)&sc[h][lane*4] = make_float4(acc[h][0], acc[h][1], acc[h][2], acc[h][3]);
  } else {
    float* dstp = qk_lds + (size_t)(wv - 1)*(H_*S_);
    #pragma unroll
    for (int h = 0; h < H_; ++h)
      *(float4*)&dstp[h*S_ + lane*4] = make_float4(acc[h][0], acc[h][1], acc[h][2], acc[h][3]);
  }
  __syncthreads();
  #pragma unroll
  for (int h = 0; h < H_; ++h)
    sc[h][tid] += qk_lds[0*(H_*S_) + h*S_ + tid]
                + qk_lds[1*(H_*S_) + h*S_ + tid]
                + qk_lds[2*(H_*S_) + h*S_ + tid];
  __syncthreads();

  // ---- softmax over s (3 heads per wave) ----
  {
    #pragma unroll
    for (int hh = 0; hh < 3; ++hh) {
      const int h = wv*3 + hh;
      float4 v = *(const float4*)(&sc[h][lane*4]);
      float m = fmaxf(fmaxf(v.x, v.y), fmaxf(v.z, v.w));
      #pragma unroll
      for (int off = 32; off > 0; off >>= 1) m = fmaxf(m, __shfl_xor(m, off));
      const float e0 = __expf(v.x - m), e1 = __expf(v.y - m),
                  e2 = __expf(v.z - m), e3 = __expf(v.w - m);
      float ss = (e0+e1)+(e2+e3);
      #pragma unroll
      for (int off = 32; off > 0; off >>= 1) ss += __shfl_xor(ss, off);
      const float inv = 1.0f / ss;
      *(float4*)(&sc[h][lane*4]) = make_float4(e0*inv, e1*inv, e2*inv, e3*inv);
    }
  }
  __syncthreads();

  // ---- wsum: thread owns dd = c*256+tid; stream s via uint4 (8 s) ----
  float wacc[H_][3];
  #pragma unroll
  for (int h = 0; h < H_; ++h) { wacc[h][0]=0.f; wacc[h][1]=0.f; wacc[h][2]=0.f; }
  const unsigned short* prow = packed + (size_t)bt*16*D_*16;
  #pragma unroll 2
  for (int s8 = 0; s8 < 32; ++s8) {
    float f[3][8];
    #pragma unroll
    for (int c = 0; c < 3; ++c) {
      const uint4 pv = *(const uint4*)(prow + ((size_t)(s8 >> 1)*D_ + c*256 + tid)*16
                                            + (s8 & 1)*8);
      f[c][0] = __uint_as_float(pv.x << 16);
      f[c][1] = __uint_as_float(pv.x & 0xFFFF0000u);
      f[c][2] = __uint_as_float(pv.y << 16);
      f[c][3] = __uint_as_float(pv.y & 0xFFFF0000u);
      f[c][4] = __uint_as_float(pv.z << 16);
      f[c][5] = __uint_as_float(pv.z & 0xFFFF0000u);
      f[c][6] = __uint_as_float(pv.w << 16);
      f[c][7] = __uint_as_float(pv.w & 0xFFFF0000u);
    }
    #pragma unroll
    for (int h = 0; h < H_; ++h) {
      const float4 a0 = *(const float4*)&sc[h][s8*8];
      const float4 a1 = *(const float4*)&sc[h][s8*8 + 4];
      #pragma unroll
      for (int c = 0; c < 3; ++c)
        wacc[h][c] += a0.x*f[c][0] + a0.y*f[c][1] + a0.z*f[c][2] + a0.w*f[c][3]
                    + a1.x*f[c][4] + a1.y*f[c][5] + a1.z*f[c][6] + a1.w*f[c][7];
    }
  }
  float* wp = wout + (size_t)bt*H_*D_;
  #pragma unroll
  for (int h = 0; h < H_; ++h)
    #pragma unroll
    for (int c = 0; c < 3; ++c)
      wp[h*D_ + c*256 + tid] = wacc[h][c];
}

// ---------------- fallback path (small workspace) ----------------
__global__ __launch_bounds__(256) void k_q(const float* __restrict__ x, float* __restrict__ q) {
  const int bd = blockIdx.x;
  const int tid = threadIdx.x;
  const float4* xp = (const float4*)(x + (size_t)bd * (W_*W_));
  float acc[8] = {0,0,0,0,0,0,0,0};
  #pragma unroll
  for (int k = 0; k < 16; ++k) {
    float4 v = xp[k*256 + tid];
    acc[k>>1] += (v.x + v.y) + (v.z + v.w);
  }
  __shared__ float part[256][9];
  #pragma unroll
  for (int i = 0; i < 8; ++i) part[tid][i] = acc[i];
  __syncthreads();
  if (tid < 64) {
    const int ti = tid >> 3, tj = tid & 7;
    float s = 0.f;
    #pragma unroll
    for (int m = 0; m < 8; ++m)
      #pragma unroll
      for (int n = 0; n < 4; ++n)
        s += part[m*32 + tj*4 + n][ti];
    const int b = bd / D_, d = bd - b*D_;
    q[(size_t)(b*T_ + tid)*D_ + d] = s * (1.0f/256.0f);
  }
}

__global__ __launch_bounds__(256) void k_attn(const float* __restrict__ x,
                                              const float* __restrict__ qkin,
                                              float* __restrict__ wout) {
  const int bt = blockIdx.x;
  const int b = bt >> 6, t = bt & 63;
  const int ti = t >> 3, tj = t & 7;
  const int tid = threadIdx.x;
  __shared__ float qkl[H_*D_];
  __shared__ float sc[H_][S_];
  const float* xb = x + (size_t)b*D_*W_*W_ + ti*16*W_ + tj*16;
  {
    const float4* src = (const float4*)(qkin + (size_t)bt*H_*D_);
    float4* dst = (float4*)qkl;
    #pragma unroll
    for (int k = 0; k < 9; ++k) dst[k*256 + tid] = src[k*256 + tid];
  }
  __syncthreads();
  float acc[H_];
  #pragma unroll
  for (int h = 0; h < H_; ++h) acc[h] = 0.f;
  #pragma unroll
  for (int c = 0; c < 3; ++c) {
    const float* chp = xb + (size_t)(3*tid + c)*(W_*W_);
    for (int blk = 0; blk < 8; ++blk) {
      float4 v[8];
      #pragma unroll
      for (int u = 0; u < 8; ++u) {
        const int pg = blk*8 + u;
        v[u] = *(const float4*)(chp + (pg>>2)*W_ + (pg&3)*4);
      }
      const int dbase = c*256 + blk*32;
      #pragma unroll
      for (int h = 0; h < H_; ++h) {
        const float4* qh = (const float4*)(qkl + h*D_ + dbase);
        float s0 = 0.f;
        #pragma unroll
        for (int u = 0; u < 8; ++u) {
          const float4 qq = qh[u];
          s0 += qq.x*v[u].x + qq.y*v[u].y + qq.z*v[u].z + qq.w*v[u].w;
        }
        acc[h] += s0;
      }
    }
  }
  #pragma unroll
  for (int h = 0; h < H_; ++h) sc[h][tid] = acc[h];
  __syncthreads();
  {
    const int wv = tid >> 6, lane = tid & 63;
    #pragma unroll
    for (int hh = 0; hh < 3; ++hh) {
      const int h = wv*3 + hh;
      float4 v = *(const float4*)(&sc[h][lane*4]);
      float m = fmaxf(fmaxf(v.x, v.y), fmaxf(v.z, v.w));
      #pragma unroll
      for (int off = 32; off > 0; off >>= 1) m = fmaxf(m, __shfl_xor(m, off));
      const float e0 = __expf(v.x - m), e1 = __expf(v.y - m),
                  e2 = __expf(v.z - m), e3 = __expf(v.w - m);
      float ss = (e0+e1)+(e2+e3);
      #pragma unroll
      for (int off = 32; off > 0; off >>= 1) ss += __shfl_xor(ss, off);
      const float inv = 1.0f / ss;
      *(float4*)(&sc[h][lane*4]) = make_float4(e0*inv, e1*inv, e2*inv, e3*inv);
    }
  }
  __syncthreads();
  float wacc[H_][3];
  #pragma unroll
  for (int h = 0; h < H_; ++h) { wacc[h][0]=0.f; wacc[h][1]=0.f; wacc[h][2]=0.f; }
  const float* xp0 = xb + (tid>>4)*W_ + (tid&15);
  for (int s = 0; s < S_; ++s) {
    const float p0 = xp0[(size_t)(3*s+0)*(W_*W_)];
    const float p1 = xp0[(size_t)(3*s+1)*(W_*W_)];
    const float p2 = xp0[(size_t)(3*s+2)*(W_*W_)];
    #pragma unroll
    for (int h = 0; h < H_; ++h) {
      const float at = sc[h][s];
      wacc[h][0] += at*p0; wacc[h][1] += at*p1; wacc[h][2] += at*p2;
    }
  }
  float* wp = wout + (size_t)bt*H_*D_;
  #pragma unroll
  for (int h = 0; h < H_; ++h)
    #pragma unroll
    for (int c = 0; c < 3; ++c)
      wp[h*D_ + c*256 + tid] = wacc[h][c];
}
// ------------------------------------------------------------------

// K4a: ctx[bt][h*64+i] = sum_d w[bt][h][d] * Wv[h*64+i][d] + bv
__global__ __launch_bounds__(256) void k_ctx(const float* __restrict__ wbuf,
                                             const float* __restrict__ ipw,
                                             const float* __restrict__ ipb,
                                             float* __restrict__ ctx) {
  const int h = blockIdx.x >> 5;
  const int bt0 = (blockIdx.x & 31) * 16;
  const int tid = threadIdx.x;
  const float* Wv = ipw + (size_t)2*D_*D_ + (size_t)h*64*D_;
  __shared__ float wt[64][65];
  __shared__ float at[16][65];
  const int i = tid & 63, qw = tid >> 6;
  float acc[4] = {0,0,0,0};
  for (int dc = 0; dc < D_; dc += 64) {
    #pragma unroll
    for (int k = 0; k < 4; ++k) {
      const int idx = k*256 + tid;
      const int r = idx >> 4, c4 = idx & 15;
      *(float4*)&wt[r][c4*4] = *(const float4*)(Wv + (size_t)r*D_ + dc + c4*4);
    }
    {
      const int r = tid >> 4, c4 = tid & 15;
      *(float4*)&at[r][c4*4] = *(const float4*)(wbuf + ((size_t)(bt0 + r)*H_ + h)*D_ + dc + c4*4);
    }
    __syncthreads();
    #pragma unroll
    for (int dd = 0; dd < 64; ++dd) {
      const float wv = wt[i][dd];
      #pragma unroll
      for (int k = 0; k < 4; ++k)
        acc[k] += at[qw + k*4][dd] * wv;
    }
    __syncthreads();
  }
  const float bvv = ipb[2*D_ + h*64 + i];
  #pragma unroll
  for (int k = 0; k < 4; ++k)
    ctx[(size_t)(bt0 + qw + k*4)*D_ + h*64 + i] = acc[k] + bvv;
}

// K4b: out[bt][j] = ctx[bt][:] . ow[j][:] + ob[j]
__global__ __launch_bounds__(256) void k_out(const float* __restrict__ ctx,
                                             const float* __restrict__ ow,
                                             const float* __restrict__ ob,
                                             float* __restrict__ out) {
  const int jt = blockIdx.x >> 5;
  const int bt0 = (blockIdx.x & 31) * 16;
  const int tid = threadIdx.x;
  const float* Wr = ow + (size_t)jt*64*D_;
  __shared__ float wt[64][65];
  __shared__ float at[16][65];
  const int i = tid & 63, qw = tid >> 6;
  float acc[4] = {0,0,0,0};
  for (int dc = 0; dc < D_; dc += 64) {
    #pragma unroll
    for (int k = 0; k < 4; ++k) {
      const int idx = k*256 + tid;
      const int r = idx >> 4, c4 = idx & 15;
      *(float4*)&wt[r][c4*4] = *(const float4*)(Wr + (size_t)r*D_ + dc + c4*4);
    }
    {
      const int r = tid >> 4, c4 = tid & 15;
      *(float4*)&at[r][c4*4] = *(const float4*)(ctx + (size_t)(bt0 + r)*D_ + dc + c4*4);
    }
    __syncthreads();
    #pragma unroll
    for (int dd = 0; dd < 64; ++dd) {
      const float wv = wt[i][dd];
      #pragma unroll
      for (int k = 0; k < 4; ++k)
        acc[k] += at[qw + k*4][dd] * wv;
    }
    __syncthreads();
  }
  const float obv = ob[jt*64 + i];
  #pragma unroll
  for (int k = 0; k < 4; ++k)
    out[(size_t)(bt0 + qw + k*4)*D_ + jt*64 + i] = acc[k] + obv;
}

extern "C" void kernel_launch(void* const* d_in, const int* in_sizes, int n_in,
                              void* d_out, int out_size, void* d_ws, size_t ws_size,
                              hipStream_t stream) {
  const float* x   = (const float*)d_in[0];
  const float* ipw = (const float*)d_in[1];
  const float* ipb = (const float*)d_in[2];
  const float* ow  = (const float*)d_in[3];
  const float* ob  = (const float*)d_in[4];
  float* out = (float*)d_out;

  float* q    = (float*)d_ws;                       // 1.5 MB
  float* qp   = q    + (size_t)BT_*D_;              // 1.5 MB
  float* qk   = qp   + (size_t)BT_*D_;              // 18.9 MB
  float* wb   = qk   + (size_t)BT_*H_*D_;           // 18.9 MB
  float* ctxb = wb   + (size_t)BT_*H_*D_;           // 1.5 MB
  unsigned short* packed = (unsigned short*)(ctxb + (size_t)BT_*D_);  // 201.3 MB

  const size_t need_main = ((size_t)BT_*D_*3 + (size_t)BT_*H_*D_*2) * 4
                         + (size_t)BT_*D_*S_*2;

  if (ws_size >= need_main) {
    k_pack <<<dim3(4096), dim3(512), 0, stream>>>(x, packed, q);
    k_qp   <<<dim3(384),  dim3(256), 0, stream>>>(q, ipw, ipb, qp);
    k_fold <<<dim3(2304), dim3(256), 0, stream>>>(qp, ipw, qk);
    k_attn3<<<dim3(BT_),  dim3(256), 0, stream>>>(packed, qk, wb);
    k_ctx  <<<dim3(384),  dim3(256), 0, stream>>>(wb, ipw, ipb, ctxb);
    k_out  <<<dim3(384),  dim3(256), 0, stream>>>(ctxb, ow, ob, out);
  } else {
    k_q    <<<dim3(8*D_), dim3(256), 0, stream>>>(x, q);
    k_qp   <<<dim3(384),  dim3(256), 0, stream>>>(q, ipw, ipb, qp);
    k_fold <<<dim3(2304), dim3(256), 0, stream>>>(qp, ipw, qk);
    k_attn <<<dim3(BT_),  dim3(256), 0, stream>>>(x, qk, wb);
    k_ctx  <<<dim3(384),  dim3(256), 0, stream>>>(wb, ipw, ipb, ctxb);
    k_out  <<<dim3(384),  dim3(256), 0, stream>>>(ctxb, ow, ob, out);
  }
}

// Round 7
// 393.852 us; speedup vs baseline: 3.0639x; 1.0487x over previous
//
#include <hip/hip_runtime.h>
#include <hip/hip_bf16.h>

#define D_ 768
#define W_ 128
#define T_ 64
#define S_ 256
#define H_ 12
#define HH_ 6
#define BT_ 512

__device__ __forceinline__ unsigned short f2bf(float f) {
  unsigned u = __float_as_uint(f);
  u = (u + 0x7FFFu + ((u >> 16) & 1u)) >> 16;
  return (unsigned short)u;
}
__device__ __forceinline__ float bfu(unsigned s) {           // low 16 bits -> float
  return __uint_as_float(s << 16);
}

// K0: pack x -> packed[bt][sc][dd][s&15] (bf16) + pooled q[bt][d] (fp32).
// Grid 4096 = (b, ti, tjp, cc); 384 threads: thread = (ch 0..47, c8 0..7),
// iterates 16 rows. Pooling = per-thread accumulate + 2-shuffle finish
// (replaces the 5-deep shuffle chain per load of the previous version).
__global__ __launch_bounds__(384) void k_pack(const float* __restrict__ x,
                                              unsigned short* __restrict__ packed,
                                              float* __restrict__ q) {
  const int blk  = blockIdx.x;
  const int cc   = blk & 15;
  const int tjp  = (blk >> 4) & 3;
  const int ti   = (blk >> 6) & 7;
  const int b    = blk >> 9;
  const int tid  = threadIdx.x;
  const int c8   = tid & 7;            // col-quad in 32 cols
  const int ch   = tid >> 3;           // 0..47
  const int btl  = c8 >> 2;
  const int btg0 = b*64 + ti*8 + tjp*2;
  const int ch0  = cc * 48;

  __shared__ unsigned short tile[48][2][260];   // 49.9 KB
  __shared__ float poolsc[48][2];

  const float* xcol = x + (size_t)b*D_*16384 + (size_t)(ch0 + ch)*16384
                        + (16*ti)*128 + 32*tjp + c8*4;

  float psum = 0.f;
  #pragma unroll
  for (int r = 0; r < 16; ++r) {
    const float4 v = *(const float4*)(xcol + r*128);
    const int px = r*16 + (c8 & 3)*4;
    unsigned lo = (unsigned)f2bf(v.x) | ((unsigned)f2bf(v.y) << 16);
    unsigned hi = (unsigned)f2bf(v.z) | ((unsigned)f2bf(v.w) << 16);
    *(uint2*)&tile[ch][btl][px] = make_uint2(lo, hi);
    psum += (v.x + v.y) + (v.z + v.w);
  }
  // reduce over the 4 col-quads of this patch (c8&3): lanes differ in bits 0-1
  psum += __shfl_xor(psum, 1);
  psum += __shfl_xor(psum, 2);
  if ((c8 & 3) == 0) poolsc[ch][btl] = psum;
  __syncthreads();

  // ---- readout: (btl, p) pairs 0..511 over 384 threads; 32B runs ----
  for (int ii = tid; ii < 512; ii += 384) {
    const int bl = ii >> 8, p = ii & 255;
    unsigned short* pbt = packed + ((size_t)(btg0 + bl)*16 + cc)*D_*16;
    #pragma unroll
    for (int c = 0; c < 3; ++c) {
      unsigned u[8];
      #pragma unroll
      for (int k2 = 0; k2 < 8; ++k2) {
        const unsigned a  = tile[3*(2*k2)     + c][bl][p];
        const unsigned b2 = tile[3*(2*k2 + 1) + c][bl][p];
        u[k2] = a | (b2 << 16);
      }
      unsigned short* dst = pbt + (size_t)(c*256 + p)*16;
      *(uint4*)(dst)     = make_uint4(u[0], u[1], u[2], u[3]);
      *(uint4*)(dst + 8) = make_uint4(u[4], u[5], u[6], u[7]);
    }
  }
  if (tid < 96) {
    const int ch2 = tid >> 1, bl = tid & 1;
    q[(size_t)(btg0 + bl)*D_ + ch0 + ch2] = poolsc[ch2][bl] * (1.0f/256.0f);
  }
}

// K2a: qp[bt][j] = q[bt][:] . Wq[j][:] + bq[j]   (tiled GEMM, 384 blocks)
__global__ __launch_bounds__(256) void k_qp(const float* __restrict__ q,
                                            const float* __restrict__ ipw,
                                            const float* __restrict__ ipb,
                                            float* __restrict__ qp) {
  const int jt = blockIdx.x >> 5;
  const int bt0 = (blockIdx.x & 31) * 16;
  const int tid = threadIdx.x;
  const float* Wr = ipw + (size_t)jt*64*D_;
  __shared__ float wt[64][65];
  __shared__ float at[16][65];
  const int i = tid & 63, qw = tid >> 6;
  float acc[4] = {0,0,0,0};
  for (int dc = 0; dc < D_; dc += 64) {
    #pragma unroll
    for (int k = 0; k < 4; ++k) {
      const int idx = k*256 + tid;
      const int r = idx >> 4, c4 = idx & 15;
      *(float4*)&wt[r][c4*4] = *(const float4*)(Wr + (size_t)r*D_ + dc + c4*4);
    }
    {
      const int r = tid >> 4, c4 = tid & 15;
      *(float4*)&at[r][c4*4] = *(const float4*)(q + (size_t)(bt0 + r)*D_ + dc + c4*4);
    }
    __syncthreads();
    #pragma unroll
    for (int dd = 0; dd < 64; ++dd) {
      const float wv = wt[i][dd];
      #pragma unroll
      for (int k = 0; k < 4; ++k)
        acc[k] += at[qw + k*4][dd] * wv;
    }
    __syncthreads();
  }
  const float bqv = ipb[jt*64 + i];
  #pragma unroll
  for (int k = 0; k < 4; ++k)
    qp[(size_t)(bt0 + qw + k*4)*D_ + jt*64 + i] = acc[k] + bqv;
}

// K2b: qk[bt][h][dd] = bf16( 0.125 * sum_i qp[bt][h*64+i] * Wk[h*64+i][dd] )
__global__ __launch_bounds__(256) void k_fold(const float* __restrict__ qp,
                                              const float* __restrict__ ipw,
                                              unsigned short* __restrict__ qkout) {
  const int btc = blockIdx.x & 15;
  const int nt  = blockIdx.x >> 4;
  const int h   = nt / 12;
  const int ddc = (nt % 12) * 64;
  const int bt0 = btc * 32;
  const int tid = threadIdx.x;
  __shared__ float qpl[32][68];
  __shared__ float wkl[64][68];
  #pragma unroll
  for (int k = 0; k < 2; ++k) {
    const int idx = k*256 + tid;
    const int r = idx >> 4, c4 = idx & 15;
    *(float4*)&qpl[r][c4*4] = *(const float4*)(qp + (size_t)(bt0 + r)*D_ + h*64 + c4*4);
  }
  #pragma unroll
  for (int k = 0; k < 4; ++k) {
    const int idx = k*256 + tid;
    const int r = idx >> 4, c4 = idx & 15;
    *(float4*)&wkl[r][c4*4] = *(const float4*)(ipw + (size_t)(D_ + h*64 + r)*D_ + ddc + c4*4);
  }
  __syncthreads();
  const int i = tid & 63, qw = tid >> 6;
  float acc[8] = {0,0,0,0,0,0,0,0};
  #pragma unroll 8
  for (int kk = 0; kk < 64; ++kk) {
    const float w = wkl[kk][i];
    #pragma unroll
    for (int k = 0; k < 8; ++k)
      acc[k] += qpl[qw + k*4][kk] * w;
  }
  #pragma unroll
  for (int k = 0; k < 8; ++k)
    qkout[((size_t)(bt0 + qw + k*4)*H_ + h)*D_ + ddc + i] = f2bf(acc[k] * 0.125f);
}

// K3: per (bt, head-half): scores -> softmax -> wsum from packed bf16.
// grid 1024: hg = blockIdx>>9, bt = blockIdx&511 (twins co-resident, share L2/L3).
// LDS 24KB: pool_lds holds qk[6][768] (f32), then exactly the 3-wave reduce scratch.
__global__ __launch_bounds__(256) void k_attn3(const unsigned short* __restrict__ packed,
                                               const unsigned short* __restrict__ qkin,
                                               float* __restrict__ wout) {
  const int hg = blockIdx.x >> 9;
  const int bt = blockIdx.x & 511;
  const int tid = threadIdx.x;
  const int wv = tid >> 6, lane = tid & 63;
  __shared__ float pool_lds[HH_ * D_];   // 18 KB: qk, then 3x(6x256) scratch
  __shared__ float sc[HH_][S_];          // 6 KB

  { // load qk (bf16) for this head-half -> f32 LDS
    const uint4* src = (const uint4*)(qkin + ((size_t)bt*H_ + hg*HH_)*D_);
    #pragma unroll
    for (int k = 0; k < 3; ++k) {
      const int idx = k*256 + tid;
      if (idx < 576) {
        const uint4 v = src[idx];
        float* d = pool_lds + idx*8;
        d[0] = bfu(v.x & 0xFFFFu); d[1] = bfu(v.x >> 16);
        d[2] = bfu(v.y & 0xFFFFu); d[3] = bfu(v.y >> 16);
        d[4] = bfu(v.z & 0xFFFFu); d[5] = bfu(v.z >> 16);
        d[6] = bfu(v.w & 0xFFFFu); d[7] = bfu(v.w >> 16);
      }
    }
  }
  __syncthreads();

  // ---- scores partials: wave owns d-quarter, lane owns (sc-chunk, s-offset) ----
  float acc[HH_][4];
  #pragma unroll
  for (int h = 0; h < HH_; ++h)
    #pragma unroll
    for (int j = 0; j < 4; ++j) acc[h][j] = 0.f;

  {
    const unsigned short* pb = packed + ((size_t)bt*16 + (lane >> 2))*D_*16 + (lane & 3)*4;
    const int d0 = wv * 192;
    #pragma unroll 4
    for (int d4 = 0; d4 < 48; ++d4) {
      const int d = d0 + d4*4;
      float f[4][4];
      #pragma unroll
      for (int dd = 0; dd < 4; ++dd) {
        const short4 pv = *(const short4*)(pb + (size_t)(d + dd)*16);
        f[dd][0] = bfu((unsigned)(unsigned short)pv.x);
        f[dd][1] = bfu((unsigned)(unsigned short)pv.y);
        f[dd][2] = bfu((unsigned)(unsigned short)pv.z);
        f[dd][3] = bfu((unsigned)(unsigned short)pv.w);
      }
      #pragma unroll
      for (int h = 0; h < HH_; ++h) {
        const float4 qv = *(const float4*)&pool_lds[h*D_ + d];
        #pragma unroll
        for (int j = 0; j < 4; ++j)
          acc[h][j] += qv.x*f[0][j] + qv.y*f[1][j] + qv.z*f[2][j] + qv.w*f[3][j];
      }
    }
  }
  __syncthreads();   // all waves done reading qk from pool_lds

  if (wv == 0) {
    #pragma unroll
    for (int h = 0; h < HH_; ++h)
      *(float4*)&sc[h][lane*4] = make_float4(acc[h][0], acc[h][1], acc[h][2], acc[h][3]);
  } else {
    float* dstp = pool_lds + (size_t)(wv - 1)*(HH_*S_);
    #pragma unroll
    for (int h = 0; h < HH_; ++h)
      *(float4*)&dstp[h*S_ + lane*4] = make_float4(acc[h][0], acc[h][1], acc[h][2], acc[h][3]);
  }
  __syncthreads();
  #pragma unroll
  for (int h = 0; h < HH_; ++h)
    sc[h][tid] += pool_lds[0*(HH_*S_) + h*S_ + tid]
                + pool_lds[1*(HH_*S_) + h*S_ + tid]
                + pool_lds[2*(HH_*S_) + h*S_ + tid];
  __syncthreads();

  // ---- softmax over s: waves 0-2 handle 2 heads each ----
  if (wv < 3) {
    #pragma unroll
    for (int hh = 0; hh < 2; ++hh) {
      const int h = wv*2 + hh;
      float4 v = *(const float4*)(&sc[h][lane*4]);
      float m = fmaxf(fmaxf(v.x, v.y), fmaxf(v.z, v.w));
      #pragma unroll
      for (int off = 32; off > 0; off >>= 1) m = fmaxf(m, __shfl_xor(m, off));
      const float e0 = __expf(v.x - m), e1 = __expf(v.y - m),
                  e2 = __expf(v.z - m), e3 = __expf(v.w - m);
      float ss = (e0+e1)+(e2+e3);
      #pragma unroll
      for (int off = 32; off > 0; off >>= 1) ss += __shfl_xor(ss, off);
      const float inv = 1.0f / ss;
      *(float4*)(&sc[h][lane*4]) = make_float4(e0*inv, e1*inv, e2*inv, e3*inv);
    }
  }
  __syncthreads();

  // ---- wsum: thread owns dd = c*256+tid; stream s via uint4 (8 s) ----
  float wacc[HH_][3];
  #pragma unroll
  for (int h = 0; h < HH_; ++h) { wacc[h][0]=0.f; wacc[h][1]=0.f; wacc[h][2]=0.f; }
  const unsigned short* prow = packed + (size_t)bt*16*D_*16;
  #pragma unroll 2
  for (int s8 = 0; s8 < 32; ++s8) {
    float f[3][8];
    #pragma unroll
    for (int c = 0; c < 3; ++c) {
      const uint4 pv = *(const uint4*)(prow + ((size_t)(s8 >> 1)*D_ + c*256 + tid)*16
                                            + (s8 & 1)*8);
      f[c][0] = bfu(pv.x & 0xFFFFu); f[c][1] = bfu(pv.x >> 16);
      f[c][2] = bfu(pv.y & 0xFFFFu); f[c][3] = bfu(pv.y >> 16);
      f[c][4] = bfu(pv.z & 0xFFFFu); f[c][5] = bfu(pv.z >> 16);
      f[c][6] = bfu(pv.w & 0xFFFFu); f[c][7] = bfu(pv.w >> 16);
    }
    #pragma unroll
    for (int h = 0; h < HH_; ++h) {
      const float4 a0 = *(const float4*)&sc[h][s8*8];
      const float4 a1 = *(const float4*)&sc[h][s8*8 + 4];
      #pragma unroll
      for (int c = 0; c < 3; ++c)
        wacc[h][c] += a0.x*f[c][0] + a0.y*f[c][1] + a0.z*f[c][2] + a0.w*f[c][3]
                    + a1.x*f[c][4] + a1.y*f[c][5] + a1.z*f[c][6] + a1.w*f[c][7];
    }
  }
  float* wp = wout + ((size_t)bt*H_ + hg*HH_)*D_;
  #pragma unroll
  for (int h = 0; h < HH_; ++h)
    #pragma unroll
    for (int c = 0; c < 3; ++c)
      wp[h*D_ + c*256 + tid] = wacc[h][c];
}

// ---------------- fallback path (small workspace) ----------------
__global__ __launch_bounds__(256) void k_q(const float* __restrict__ x, float* __restrict__ q) {
  const int bd = blockIdx.x;
  const int tid = threadIdx.x;
  const float4* xp = (const float4*)(x + (size_t)bd * (W_*W_));
  float acc[8] = {0,0,0,0,0,0,0,0};
  #pragma unroll
  for (int k = 0; k < 16; ++k) {
    float4 v = xp[k*256 + tid];
    acc[k>>1] += (v.x + v.y) + (v.z + v.w);
  }
  __shared__ float part[256][9];
  #pragma unroll
  for (int i = 0; i < 8; ++i) part[tid][i] = acc[i];
  __syncthreads();
  if (tid < 64) {
    const int ti = tid >> 3, tj = tid & 7;
    float s = 0.f;
    #pragma unroll
    for (int m = 0; m < 8; ++m)
      #pragma unroll
      for (int n = 0; n < 4; ++n)
        s += part[m*32 + tj*4 + n][ti];
    const int b = bd / D_, d = bd - b*D_;
    q[(size_t)(b*T_ + tid)*D_ + d] = s * (1.0f/256.0f);
  }
}

__global__ __launch_bounds__(256) void k_attn(const float* __restrict__ x,
                                              const unsigned short* __restrict__ qkin,
                                              float* __restrict__ wout) {
  const int bt = blockIdx.x;
  const int b = bt >> 6, t = bt & 63;
  const int ti = t >> 3, tj = t & 7;
  const int tid = threadIdx.x;
  __shared__ float qkl[H_*D_];
  __shared__ float sc[H_][S_];
  const float* xb = x + (size_t)b*D_*W_*W_ + ti*16*W_ + tj*16;
  {
    const uint4* src = (const uint4*)(qkin + (size_t)bt*H_*D_);
    #pragma unroll
    for (int k = 0; k < 5; ++k) {
      const int idx = k*256 + tid;
      if (idx < 1152) {
        const uint4 v = src[idx];
        float* d = qkl + idx*8;
        d[0] = bfu(v.x & 0xFFFFu); d[1] = bfu(v.x >> 16);
        d[2] = bfu(v.y & 0xFFFFu); d[3] = bfu(v.y >> 16);
        d[4] = bfu(v.z & 0xFFFFu); d[5] = bfu(v.z >> 16);
        d[6] = bfu(v.w & 0xFFFFu); d[7] = bfu(v.w >> 16);
      }
    }
  }
  __syncthreads();
  float acc[H_];
  #pragma unroll
  for (int h = 0; h < H_; ++h) acc[h] = 0.f;
  #pragma unroll
  for (int c = 0; c < 3; ++c) {
    const float* chp = xb + (size_t)(3*tid + c)*(W_*W_);
    for (int blk = 0; blk < 8; ++blk) {
      float4 v[8];
      #pragma unroll
      for (int u = 0; u < 8; ++u) {
        const int pg = blk*8 + u;
        v[u] = *(const float4*)(chp + (pg>>2)*W_ + (pg&3)*4);
      }
      const int dbase = c*256 + blk*32;
      #pragma unroll
      for (int h = 0; h < H_; ++h) {
        const float4* qh = (const float4*)(qkl + h*D_ + dbase);
        float s0 = 0.f;
        #pragma unroll
        for (int u = 0; u < 8; ++u) {
          const float4 qq = qh[u];
          s0 += qq.x*v[u].x + qq.y*v[u].y + qq.z*v[u].z + qq.w*v[u].w;
        }
        acc[h] += s0;
      }
    }
  }
  #pragma unroll
  for (int h = 0; h < H_; ++h) sc[h][tid] = acc[h];
  __syncthreads();
  {
    const int wv = tid >> 6, lane = tid & 63;
    #pragma unroll
    for (int hh = 0; hh < 3; ++hh) {
      const int h = wv*3 + hh;
      float4 v = *(const float4*)(&sc[h][lane*4]);
      float m = fmaxf(fmaxf(v.x, v.y), fmaxf(v.z, v.w));
      #pragma unroll
      for (int off = 32; off > 0; off >>= 1) m = fmaxf(m, __shfl_xor(m, off));
      const float e0 = __expf(v.x - m), e1 = __expf(v.y - m),
                  e2 = __expf(v.z - m), e3 = __expf(v.w - m);
      float ss = (e0+e1)+(e2+e3);
      #pragma unroll
      for (int off = 32; off > 0; off >>= 1) ss += __shfl_xor(ss, off);
      const float inv = 1.0f / ss;
      *(float4*)(&sc[h][lane*4]) = make_float4(e0*inv, e1*inv, e2*inv, e3*inv);
    }
  }
  __syncthreads();
  float wacc[H_][3];
  #pragma unroll
  for (int h = 0; h < H_; ++h) { wacc[h][0]=0.f; wacc[h][1]=0.f; wacc[h][2]=0.f; }
  const float* xp0 = xb + (tid>>4)*W_ + (tid&15);
  for (int s = 0; s < S_; ++s) {
    const float p0 = xp0[(size_t)(3*s+0)*(W_*W_)];
    const float p1 = xp0[(size_t)(3*s+1)*(W_*W_)];
    const float p2 = xp0[(size_t)(3*s+2)*(W_*W_)];
    #pragma unroll
    for (int h = 0; h < H_; ++h) {
      const float at = sc[h][s];
      wacc[h][0] += at*p0; wacc[h][1] += at*p1; wacc[h][2] += at*p2;
    }
  }
  float* wp = wout + (size_t)bt*H_*D_;
  #pragma unroll
  for (int h = 0; h < H_; ++h)
    #pragma unroll
    for (int c = 0; c < 3; ++c)
      wp[h*D_ + c*256 + tid] = wacc[h][c];
}
// ------------------------------------------------------------------

// K4a: ctx[bt][h*64+i] = sum_d w[bt][h][d] * Wv[h*64+i][d] + bv
__global__ __launch_bounds__(256) void k_ctx(const float* __restrict__ wbuf,
                                             const float* __restrict__ ipw,
                                             const float* __restrict__ ipb,
                                             float* __restrict__ ctx) {
  const int h = blockIdx.x >> 5;
  const int bt0 = (blockIdx.x & 31) * 16;
  const int tid = threadIdx.x;
  const float* Wv = ipw + (size_t)2*D_*D_ + (size_t)h*64*D_;
  __shared__ float wt[64][65];
  __shared__ float at[16][65];
  const int i = tid & 63, qw = tid >> 6;
  float acc[4] = {0,0,0,0};
  for (int dc = 0; dc < D_; dc += 64) {
    #pragma unroll
    for (int k = 0; k < 4; ++k) {
      const int idx = k*256 + tid;
      const int r = idx >> 4, c4 = idx & 15;
      *(float4*)&wt[r][c4*4] = *(const float4*)(Wv + (size_t)r*D_ + dc + c4*4);
    }
    {
      const int r = tid >> 4, c4 = tid & 15;
      *(float4*)&at[r][c4*4] = *(const float4*)(wbuf + ((size_t)(bt0 + r)*H_ + h)*D_ + dc + c4*4);
    }
    __syncthreads();
    #pragma unroll
    for (int dd = 0; dd < 64; ++dd) {
      const float wv = wt[i][dd];
      #pragma unroll
      for (int k = 0; k < 4; ++k)
        acc[k] += at[qw + k*4][dd] * wv;
    }
    __syncthreads();
  }
  const float bvv = ipb[2*D_ + h*64 + i];
  #pragma unroll
  for (int k = 0; k < 4; ++k)
    ctx[(size_t)(bt0 + qw + k*4)*D_ + h*64 + i] = acc[k] + bvv;
}

// K4b: out[bt][j] = ctx[bt][:] . ow[j][:] + ob[j]
__global__ __launch_bounds__(256) void k_out(const float* __restrict__ ctx,
                                             const float* __restrict__ ow,
                                             const float* __restrict__ ob,
                                             float* __restrict__ out) {
  const int jt = blockIdx.x >> 5;
  const int bt0 = (blockIdx.x & 31) * 16;
  const int tid = threadIdx.x;
  const float* Wr = ow + (size_t)jt*64*D_;
  __shared__ float wt[64][65];
  __shared__ float at[16][65];
  const int i = tid & 63, qw = tid >> 6;
  float acc[4] = {0,0,0,0};
  for (int dc = 0; dc < D_; dc += 64) {
    #pragma unroll
    for (int k = 0; k < 4; ++k) {
      const int idx = k*256 + tid;
      const int r = idx >> 4, c4 = idx & 15;
      *(float4*)&wt[r][c4*4] = *(const float4*)(Wr + (size_t)r*D_ + dc + c4*4);
    }
    {
      const int r = tid >> 4, c4 = tid & 15;
      *(float4*)&at[r][c4*4] = *(const float4*)(ctx + (size_t)(bt0 + r)*D_ + dc + c4*4);
    }
    __syncthreads();
    #pragma unroll
    for (int dd = 0; dd < 64; ++dd) {
      const float wv = wt[i][dd];
      #pragma unroll
      for (int k = 0; k < 4; ++k)
        acc[k] += at[qw + k*4][dd] * wv;
    }
    __syncthreads();
  }
  const float obv = ob[jt*64 + i];
  #pragma unroll
  for (int k = 0; k < 4; ++k)
    out[(size_t)(bt0 + qw + k*4)*D_ + jt*64 + i] = acc[k] + obv;
}

extern "C" void kernel_launch(void* const* d_in, const int* in_sizes, int n_in,
                              void* d_out, int out_size, void* d_ws, size_t ws_size,
                              hipStream_t stream) {
  const float* x   = (const float*)d_in[0];
  const float* ipw = (const float*)d_in[1];
  const float* ipb = (const float*)d_in[2];
  const float* ow  = (const float*)d_in[3];
  const float* ob  = (const float*)d_in[4];
  float* out = (float*)d_out;

  float* q    = (float*)d_ws;                       // 1.5 MB
  float* qp   = q    + (size_t)BT_*D_;              // 1.5 MB
  unsigned short* qk = (unsigned short*)(qp + (size_t)BT_*D_);   // bf16, region reserved as before
  float* wb   = qp   + (size_t)BT_*D_ + (size_t)BT_*H_*D_;       // 18.9 MB
  float* ctxb = wb   + (size_t)BT_*H_*D_;           // 1.5 MB
  unsigned short* packed = (unsigned short*)(ctxb + (size_t)BT_*D_);  // 201.3 MB

  const size_t need_main = ((size_t)BT_*D_*3 + (size_t)BT_*H_*D_*2) * 4
                         + (size_t)BT_*D_*S_*2;

  if (ws_size >= need_main) {
    k_pack <<<dim3(4096), dim3(384), 0, stream>>>(x, packed, q);
    k_qp   <<<dim3(384),  dim3(256), 0, stream>>>(q, ipw, ipb, qp);
    k_fold <<<dim3(2304), dim3(256), 0, stream>>>(qp, ipw, qk);
    k_attn3<<<dim3(1024), dim3(256), 0, stream>>>(packed, qk, wb);
    k_ctx  <<<dim3(384),  dim3(256), 0, stream>>>(wb, ipw, ipb, ctxb);
    k_out  <<<dim3(384),  dim3(256), 0, stream>>>(ctxb, ow, ob, out);
  } else {
    k_q    <<<dim3(8*D_), dim3(256), 0, stream>>>(x, q);
    k_qp   <<<dim3(384),  dim3(256), 0, stream>>>(q, ipw, ipb, qp);
    k_fold <<<dim3(2304), dim3(256), 0, stream>>>(qp, ipw, qk);
    k_attn <<<dim3(BT_),  dim3(256), 0, stream>>>(x, qk, wb);
    k_ctx  <<<dim3(384),  dim3(256), 0, stream>>>(wb, ipw, ipb, ctxb);
    k_out  <<<dim3(384),  dim3(256), 0, stream>>>(ctxb, ow, ob, out);
  }
}